// Round 5
// baseline (1778.284 us; speedup 1.0000x reference)
//
#include <hip/hip_runtime.h>
#include <cstdint>

#define TT 2048
#define CCH 1024
#define FFD 4096
#define EPSV 1e-5f
#define NCHK 32
#define CHKL 64   // TT / NCHK

typedef __attribute__((ext_vector_type(4))) float floatx4;
typedef __attribute__((ext_vector_type(8))) short shortx8;

__device__ __forceinline__ unsigned short f32_to_bf16(float f){
  union { float f; unsigned int u; } x; x.f = f;
  unsigned int r = x.u + 0x7fffu + ((x.u >> 16) & 1u);
  return (unsigned short)(r >> 16);
}
__device__ __forceinline__ float bf16_to_f32(unsigned short h){
  union { unsigned int u; float f; } x; x.u = ((unsigned int)h) << 16;
  return x.f;
}
__device__ __forceinline__ float wave_sum(float v){
  #pragma unroll
  for (int o = 32; o > 0; o >>= 1) v += __shfl_down(v, o, 64);
  return v;
}
__device__ __forceinline__ void async16(const void* g, void* l){
  __builtin_amdgcn_global_load_lds((const __attribute__((address_space(1))) void*)g,
                                   (__attribute__((address_space(3))) void*)l, 16, 0, 0);
}

// ---------------- fp32 -> bf16 weight conversion (7 segments fused) ----------------
struct CvtArgs {
  const float* s[7];
  unsigned short* d[7];
  int n4[7];
};
__global__ __launch_bounds__(256) void cvt7_kernel(CvtArgs a){
  const int seg = blockIdx.y;
  const float* __restrict__ s = a.s[seg];
  unsigned short* __restrict__ d = a.d[seg];
  const int n4 = a.n4[seg];
  for (int i = blockIdx.x * 256 + threadIdx.x; i < n4; i += gridDim.x * 256) {
    float4 v = ((const float4*)s)[i];
    union { unsigned short u[4]; uint2 p; } o;
    o.u[0] = f32_to_bf16(v.x); o.u[1] = f32_to_bf16(v.y);
    o.u[2] = f32_to_bf16(v.z); o.u[3] = f32_to_bf16(v.w);
    *(uint2*)&d[(long)i * 4] = o.p;
  }
}

// ---------------- ln0: x_in -> x (fp32) ----------------
__global__ __launch_bounds__(256) void ln0_kernel(const float* __restrict__ xin,
    const float* __restrict__ w, const float* __restrict__ b, float* __restrict__ xo){
  const int row = blockIdx.x, tid = threadIdx.x;
  const float* xr = xin + (long)row * CCH;
  float c4[4]; float s = 0.f, s2 = 0.f;
  #pragma unroll
  for (int j = 0; j < 4; j++){ c4[j] = xr[tid + j*256]; s += c4[j]; s2 += c4[j]*c4[j]; }
  s = wave_sum(s); s2 = wave_sum(s2);
  __shared__ float red[2][4];
  const int wid = tid >> 6, lane = tid & 63;
  if (lane == 0){ red[0][wid] = s; red[1][wid] = s2; }
  __syncthreads();
  const float S  = red[0][0]+red[0][1]+red[0][2]+red[0][3];
  const float S2 = red[1][0]+red[1][1]+red[1][2]+red[1][3];
  const float inv = 1.f / CCH;
  const float m = S * inv;
  const float rs = rsqrtf(S2 * inv - m*m + EPSV);
  float* xout = xo + (long)row * CCH;
  #pragma unroll
  for (int j = 0; j < 4; j++){ int c = tid + j*256; xout[c] = (c4[j]-m)*rs*w[c] + b[c]; }
}

// ---------------- fused LN + time-shift + mix -> bf16 ----------------
template<int NOUT>
__global__ __launch_bounds__(256) void ln_mix(
    const float* __restrict__ x,
    const float* __restrict__ lw, const float* __restrict__ lb,
    const float* __restrict__ mk, const float* __restrict__ mv, const float* __restrict__ mr,
    unsigned short* __restrict__ xk, unsigned short* __restrict__ xv, unsigned short* __restrict__ xr)
{
  const int row = blockIdx.x;
  const int t = row & (TT - 1);
  const int tid = threadIdx.x;
  const float* xc = x + (long)row * CCH;
  const float* xp = xc - CCH;
  float c4[4], p4[4];
  float s1=0.f, s2=0.f, s3=0.f, s4=0.f;
  #pragma unroll
  for (int j = 0; j < 4; j++){
    const int c = tid + j*256;
    c4[j] = xc[c];
    p4[j] = (t > 0) ? xp[c] : 0.f;
    s1 += c4[j]; s2 += c4[j]*c4[j];
    s3 += p4[j]; s4 += p4[j]*p4[j];
  }
  s1 = wave_sum(s1); s2 = wave_sum(s2); s3 = wave_sum(s3); s4 = wave_sum(s4);
  __shared__ float red[4][4];
  const int wid = tid >> 6, lane = tid & 63;
  if (lane == 0){ red[wid][0]=s1; red[wid][1]=s2; red[wid][2]=s3; red[wid][3]=s4; }
  __syncthreads();
  const float S1 = red[0][0]+red[1][0]+red[2][0]+red[3][0];
  const float S2 = red[0][1]+red[1][1]+red[2][1]+red[3][1];
  const float S3 = red[0][2]+red[1][2]+red[2][2]+red[3][2];
  const float S4 = red[0][3]+red[1][3]+red[2][3]+red[3][3];
  const float inv = 1.f / CCH;
  const float m1 = S1*inv; const float r1 = rsqrtf(S2*inv - m1*m1 + EPSV);
  const float m0 = S3*inv; const float r0 = rsqrtf(S4*inv - m0*m0 + EPSV);
  #pragma unroll
  for (int j = 0; j < 4; j++){
    const int c = tid + j*256;
    const long o = (long)row * CCH + c;
    const float wv = lw[c], bv = lb[c];
    const float h  = (c4[j]-m1)*r1*wv + bv;
    const float hp = (t > 0) ? ((p4[j]-m0)*r0*wv + bv) : 0.f;
    const float a = mk[c]; xk[o] = f32_to_bf16(h*a + hp*(1.f-a));
    if (NOUT == 3){ const float q = mv[c]; xv[o] = f32_to_bf16(h*q + hp*(1.f-q)); }
    const float g = mr[c]; xr[o] = f32_to_bf16(h*g + hp*(1.f-g));
  }
}

// ---------------- WKV blocked scan ----------------
__global__ __launch_bounds__(256) void wkv_pass1(
    const unsigned short* __restrict__ kin, const unsigned short* __restrict__ vin,
    const float* __restrict__ td,
    float* __restrict__ sta, float* __restrict__ stb, float* __restrict__ stp)
{
  const int c = blockIdx.x * 256 + threadIdx.x;
  const int chunk = blockIdx.y, b = blockIdx.z;
  const float w = -__expf(td[c]);
  const long base = ((long)b * TT + (long)chunk * CHKL) * CCH + c;
  float aa = 0.f, bb = 0.f, pp = -1e38f;
  for (int t0 = 0; t0 < CHKL; t0 += 8) {
    float kr[8], vr[8];
    #pragma unroll
    for (int j = 0; j < 8; j++){
      const long o = base + (long)(t0 + j) * CCH;
      kr[j] = bf16_to_f32(kin[o]);
      vr[j] = bf16_to_f32(vin[o]);
    }
    #pragma unroll
    for (int j = 0; j < 8; j++){
      const float kk = kr[j], vv = vr[j];
      const float ww2 = pp + w;
      const float qq2 = fmaxf(ww2, kk);
      const float e1b = __expf(ww2 - qq2), e2b = __expf(kk - qq2);
      aa = e1b*aa + e2b*vv; bb = e1b*bb + e2b; pp = qq2;
    }
  }
  const long si = (long)chunk * 4096 + b * CCH + c;
  sta[si] = aa; stb[si] = bb; stp[si] = pp;
}

__global__ __launch_bounds__(256) void wkv_combine(
    const float* __restrict__ td,
    const float* __restrict__ sta, const float* __restrict__ stb, const float* __restrict__ stp,
    float* __restrict__ ina, float* __restrict__ inb, float* __restrict__ inp)
{
  const int idx = blockIdx.x * 256 + threadIdx.x;   // b*C + c
  const int c = idx & (CCH - 1);
  const float wn = -__expf(td[c]) * (float)CHKL;
  float a = 0.f, b = 0.f, p = -1e38f;
  for (int j0 = 0; j0 < NCHK; j0 += 8) {
    float la[8], lb[8], lp[8];
    #pragma unroll
    for (int j = 0; j < 8; j++){
      const long si = (long)(j0 + j) * 4096 + idx;
      la[j] = sta[si]; lb[j] = stb[si]; lp[j] = stp[si];
    }
    #pragma unroll
    for (int j = 0; j < 8; j++){
      const long si = (long)(j0 + j) * 4096 + idx;
      ina[si] = a; inb[si] = b; inp[si] = p;
      const float pd = p + wn;
      const float q = fmaxf(pd, lp[j]);
      const float e1 = __expf(pd - q), e2 = __expf(lp[j] - q);
      a = e1*a + e2*la[j]; b = e1*b + e2*lb[j]; p = q;
    }
  }
}

__global__ __launch_bounds__(256) void wkv_pass2(
    const unsigned short* __restrict__ kin, const unsigned short* __restrict__ vin,
    const unsigned short* __restrict__ srin,
    const float* __restrict__ td, const float* __restrict__ tf,
    const float* __restrict__ ina, const float* __restrict__ inb, const float* __restrict__ inp,
    unsigned short* __restrict__ out)
{
  const int c = blockIdx.x * 256 + threadIdx.x;
  const int chunk = blockIdx.y, b = blockIdx.z;
  const float w = -__expf(td[c]);
  const float u = tf[c];
  const long si = (long)chunk * 4096 + b * CCH + c;
  float aa = ina[si], bb = inb[si], pp = inp[si];
  const long base = ((long)b * TT + (long)chunk * CHKL) * CCH + c;
  for (int t0 = 0; t0 < CHKL; t0 += 8) {
    float kr[8], vr[8], sr[8];
    #pragma unroll
    for (int j = 0; j < 8; j++){
      const long o = base + (long)(t0 + j) * CCH;
      kr[j] = bf16_to_f32(kin[o]);
      vr[j] = bf16_to_f32(vin[o]);
      sr[j] = bf16_to_f32(srin[o]);
    }
    #pragma unroll
    for (int j = 0; j < 8; j++){
      const float kk = kr[j], vv = vr[j];
      const float ww = u + kk;
      const float qq = fmaxf(pp, ww);
      const float e1 = __expf(pp - qq), e2 = __expf(ww - qq);
      const float outv = (e1*aa + e2*vv) / (e1*bb + e2);
      const float ww2 = pp + w;
      const float qq2 = fmaxf(ww2, kk);
      const float e1b = __expf(ww2 - qq2), e2b = __expf(kk - qq2);
      aa = e1b*aa + e2b*vv; bb = e1b*bb + e2b; pp = qq2;
      out[base + (long)(t0 + j) * CCH] = f32_to_bf16(sr[j] * outv);
    }
  }
}

// ---------------- bf16 MFMA GEMM: C[M,N] = A[M,K] * W[N,K]^T ----------------
// Single-barrier double-buffered pipeline, BK=32 stages (2 x 8KB per matrix =
// 32 KB total LDS, same occupancy as R4). Loads for stage s+1 are issued
// BEFORE the MFMA block of stage s, so the compiler's vmcnt(0)-before-barrier
// drains loads that have had a full MFMA stage to complete.
// Swizzle: LDS line = row pair (128 B); logical (row, chunk[0..3]) stored at
// slot ((chunk + 4*(row&1)) ^ (line&7)). Frag reads hit each 4-bank group
// exactly 2x per 16 lanes -> conflict-free (2-way is free, m136).
#define BM 128
#define BN 128

enum { EP_BF16 = 0, EP_SIG = 1, EP_RELU2 = 2, EP_ADD = 3, EP_MULADD = 4, EP_KVR = 5, EP_FFN1 = 6 };

template<int EPI>
__global__ __launch_bounds__(256) void gemm_bt(
    const unsigned short* __restrict__ A,
    const unsigned short* __restrict__ W,
    int N, const int K,
    unsigned short* __restrict__ outb,
    float* __restrict__ xres,
    const unsigned short* __restrict__ rr,
    const unsigned short* __restrict__ A2,
    const unsigned short* __restrict__ W2,
    unsigned short* __restrict__ outb2,
    const int N2)
{
  const int bm = blockIdx.x, bn = blockIdx.y;
  bool sig = false;
  if (EPI == EP_KVR) {
    const long z = blockIdx.z;
    const long Mfull = (long)gridDim.x * BM;
    A    += z * Mfull * K;
    W    += z * (long)N * K;
    outb += z * Mfull * N;
    sig = (blockIdx.z == 2);
  }
  if (EPI == EP_FFN1) {
    if (blockIdx.z == 1) {
      if (bn >= N2 / BN) return;   // uniform early-exit, before any barrier
      A = A2; W = W2; outb = outb2; N = N2; sig = true;
    }
  }
  __shared__ unsigned short lA[2 * 4096];   // 2 x 8 KB
  __shared__ unsigned short lW[2 * 4096];
  const int tid = threadIdx.x;
  const int wid = tid >> 6, lane = tid & 63;
  const int wm = (wid >> 1) * 64, wn = (wid & 1) * 64;
  const int quad = lane >> 4, r16 = lane & 15;

  // staging mapping: physical chunk P (0..511) -> line = P>>3, slot = P&7;
  // logical slot sp = slot ^ (line&7); row = 2*line + (sp>>2); chunk = sp&3
  int rowS[2], chkS[2];
  #pragma unroll
  for (int i = 0; i < 2; i++) {
    const int P = i * 256 + tid;
    const int line = P >> 3, slot = P & 7;
    const int sp = slot ^ (line & 7);
    rowS[i] = 2 * line + (sp >> 2);
    chkS[i] = sp & 3;
  }
  const unsigned short* Ag0 = A + (long)(bm * BM + rowS[0]) * K + chkS[0] * 8;
  const unsigned short* Ag1 = A + (long)(bm * BM + rowS[1]) * K + chkS[1] * 8;
  const unsigned short* Wg0 = W + (long)(bn * BN + rowS[0]) * K + chkS[0] * 8;
  const unsigned short* Wg1 = W + (long)(bn * BN + rowS[1]) * K + chkS[1] * 8;
  const int ldsP0 = tid * 8;            // shorts
  const int ldsP1 = (256 + tid) * 8;

  // frag read: row r = wbase + r16; line&7 = r16>>1; slot = (quad + 4*(r&1)) ^ (r16>>1)
  const int laneOff = (r16 >> 1) * 64 + (((quad + ((r16 & 1) << 2)) ^ (r16 >> 1)) * 8);

  const floatx4 zf = {0.f, 0.f, 0.f, 0.f};
  floatx4 acc[4][4];
  #pragma unroll
  for (int i = 0; i < 4; i++)
    #pragma unroll
    for (int j = 0; j < 4; j++) acc[i][j] = zf;

  const int nst = K >> 5;
  int buf = 0;
  // preload stage 0
  async16(Ag0, &lA[ldsP0]); async16(Ag1, &lA[ldsP1]);
  async16(Wg0, &lW[ldsP0]); async16(Wg1, &lW[ldsP1]);
  __syncthreads();
  for (int s = 0; s < nst; s++) {
    const int nb = buf ^ 1;
    if (s + 1 < nst) {
      const int k0 = (s + 1) << 5;
      async16(Ag0 + k0, &lA[nb * 4096 + ldsP0]);
      async16(Ag1 + k0, &lA[nb * 4096 + ldsP1]);
      async16(Wg0 + k0, &lW[nb * 4096 + ldsP0]);
      async16(Wg1 + k0, &lW[nb * 4096 + ldsP1]);
    }
    shortx8 af[4], bf[4];
    #pragma unroll
    for (int m = 0; m < 4; m++) af[m] = *(const shortx8*)&lA[buf * 4096 + (wm + m * 16) * 32 + laneOff];
    #pragma unroll
    for (int n = 0; n < 4; n++) bf[n] = *(const shortx8*)&lW[buf * 4096 + (wn + n * 16) * 32 + laneOff];
    #pragma unroll
    for (int m = 0; m < 4; m++)
      #pragma unroll
      for (int n = 0; n < 4; n++)
        acc[m][n] = __builtin_amdgcn_mfma_f32_16x16x32_bf16(af[m], bf[n], acc[m][n], 0, 0, 0);
    __syncthreads();
    buf = nb;
  }

  const int colBase = bn * BN + wn + r16;
  #pragma unroll
  for (int m = 0; m < 4; m++) {
    const int rowBase = bm * BM + wm + m * 16 + quad * 4;
    #pragma unroll
    for (int n = 0; n < 4; n++) {
      const int col = colBase + n * 16;
      #pragma unroll
      for (int r = 0; r < 4; r++) {
        const long idx = (long)(rowBase + r) * N + col;
        const float val = acc[m][n][r];
        if (EPI == EP_KVR)       outb[idx] = sig ? f32_to_bf16(1.f / (1.f + __expf(-val)))
                                                 : f32_to_bf16(val);
        else if (EPI == EP_FFN1) {
          if (sig) outb[idx] = f32_to_bf16(1.f / (1.f + __expf(-val)));
          else     { const float t = val > 0.f ? val : 0.f; outb[idx] = f32_to_bf16(t * t); }
        }
        else if (EPI == EP_ADD)  xres[idx] += val;
        else if (EPI == EP_MULADD) xres[idx] = fmaf(bf16_to_f32(rr[idx]), val, xres[idx]);
        else                     outb[idx] = f32_to_bf16(val);
      }
    }
  }
}

extern "C" void kernel_launch(void* const* d_in, const int* in_sizes, int n_in,
                              void* d_out, int out_size, void* d_ws, size_t ws_size,
                              hipStream_t stream)
{
  const float* x_in       = (const float*)d_in[0];
  const float* ln0_w      = (const float*)d_in[1];
  const float* ln0_b      = (const float*)d_in[2];
  const float* ln1_w      = (const float*)d_in[3];
  const float* ln1_b      = (const float*)d_in[4];
  const float* ln2_w      = (const float*)d_in[5];
  const float* ln2_b      = (const float*)d_in[6];
  const float* time_decay = (const float*)d_in[7];
  const float* time_first = (const float*)d_in[8];
  const float* tmk        = (const float*)d_in[9];
  const float* tmv        = (const float*)d_in[10];
  const float* tmr        = (const float*)d_in[11];
  const float* Wk         = (const float*)d_in[12];
  const float* Wv         = (const float*)d_in[13];
  const float* Wr         = (const float*)d_in[14];
  const float* Wo         = (const float*)d_in[15];
  const float* cmk        = (const float*)d_in[16];
  const float* cmr        = (const float*)d_in[17];
  const float* Wck        = (const float*)d_in[18];
  const float* Wcv        = (const float*)d_in[19];
  const float* Wcr        = (const float*)d_in[20];
  float* x = (float*)d_out;

  const int M = 4 * TT;                 // 8192 rows
  const long lCC = (long)CCH * CCH;
  const long lFC = (long)FFD * CCH;
  const long MC  = (long)M * CCH;

  unsigned short* wsl  = (unsigned short*)d_ws;
  unsigned short* wkb  = wsl;
  unsigned short* wvb  = wkb + lCC;
  unsigned short* wrb  = wvb + lCC;
  unsigned short* wob  = wrb + lCC;
  unsigned short* wcrb = wob + lCC;
  unsigned short* wckb = wcrb + lCC;
  unsigned short* wcvb = wckb + lFC;
  unsigned short* xk   = wcvb + lFC;
  unsigned short* xv   = xk + MC;
  unsigned short* xr   = xv + MC;
  unsigned short* kbuf = xr + MC;       // region reused as kf [M,F]
  unsigned short* vbuf = kbuf + MC;
  unsigned short* sbuf = vbuf + MC;
  unsigned short* kfb  = kbuf;
  unsigned short* rrb  = kbuf + (long)M * FFD;

  // WKV scan state in the (dead between GEMMs) xk region
  float* sta = (float*)xk;
  float* stb = sta + (long)NCHK * 4096;
  float* stp = stb + (long)NCHK * 4096;
  float* ina = stp + (long)NCHK * 4096;
  float* inb = ina + (long)NCHK * 4096;
  float* inp = inb + (long)NCHK * 4096;

  ln0_kernel<<<M, 256, 0, stream>>>(x_in, ln0_w, ln0_b, x);

  const dim3 g1(M / BM, CCH / BN);      // (64, 8)
  const dim3 gkvr(M / BM, CCH / BN, 3); // (64, 8, 3)
  const dim3 gffn(M / BM, FFD / BN, 2); // (64, 32, 2): z0 = key-GEMM relu2, z1 = r-GEMM sigmoid
  const dim3 gw(CCH / 256, NCHK, 4);    // (4, 32, 4)

  for (int l = 0; l < 4; l++) {
    CvtArgs ca;
    ca.s[0] = Wk  + (long)l * lCC; ca.d[0] = wkb;  ca.n4[0] = (int)(lCC / 4);
    ca.s[1] = Wv  + (long)l * lCC; ca.d[1] = wvb;  ca.n4[1] = (int)(lCC / 4);
    ca.s[2] = Wr  + (long)l * lCC; ca.d[2] = wrb;  ca.n4[2] = (int)(lCC / 4);
    ca.s[3] = Wo  + (long)l * lCC; ca.d[3] = wob;  ca.n4[3] = (int)(lCC / 4);
    ca.s[4] = Wcr + (long)l * lCC; ca.d[4] = wcrb; ca.n4[4] = (int)(lCC / 4);
    ca.s[5] = Wck + (long)l * lFC; ca.d[5] = wckb; ca.n4[5] = (int)(lFC / 4);
    ca.s[6] = Wcv + (long)l * lFC; ca.d[6] = wcvb; ca.n4[6] = (int)(lFC / 4);
    cvt7_kernel<<<dim3(512, 7), 256, 0, stream>>>(ca);

    const float* td_l = time_decay + l*CCH;
    const float* tf_l = time_first + l*CCH;

    // --- TimeMix ---
    ln_mix<3><<<M, 256, 0, stream>>>(x, ln1_w + l*CCH, ln1_b + l*CCH,
                                     tmk + l*CCH, tmv + l*CCH, tmr + l*CCH, xk, xv, xr);
    gemm_bt<EP_KVR><<<gkvr, 256, 0, stream>>>(xk, wkb, CCH, CCH, kbuf, nullptr, nullptr,
                                              nullptr, nullptr, nullptr, 0);
    wkv_pass1 <<<gw, 256, 0, stream>>>(kbuf, vbuf, td_l, sta, stb, stp);
    wkv_combine<<<16, 256, 0, stream>>>(td_l, sta, stb, stp, ina, inb, inp);
    wkv_pass2 <<<gw, 256, 0, stream>>>(kbuf, vbuf, sbuf, td_l, tf_l, ina, inb, inp, xv);
    gemm_bt<EP_ADD ><<<g1, 256, 0, stream>>>(xv, wob, CCH, CCH, nullptr, x, nullptr,
                                             nullptr, nullptr, nullptr, 0);

    // --- ChannelMix ---
    ln_mix<2><<<M, 256, 0, stream>>>(x, ln2_w + l*CCH, ln2_b + l*CCH,
                                     cmk + l*CCH, nullptr, cmr + l*CCH, xk, nullptr, xr);
    gemm_bt<EP_FFN1><<<gffn, 256, 0, stream>>>(xk, wckb, FFD, CCH, kfb, nullptr, nullptr,
                                               xr, wcrb, rrb, CCH);
    gemm_bt<EP_MULADD><<<g1, 256, 0, stream>>>(kfb, wcvb, CCH, FFD, nullptr, x, rrb,
                                               nullptr, nullptr, nullptr, 0);
  }
}

// Round 6
// 1704.763 us; speedup vs baseline: 1.0431x; 1.0431x over previous
//
#include <hip/hip_runtime.h>
#include <cstdint>

#define TT 2048
#define CCH 1024
#define FFD 4096
#define EPSV 1e-5f
#define NCHK 32
#define CHKL 64   // TT / NCHK

typedef __attribute__((ext_vector_type(4))) float floatx4;
typedef __attribute__((ext_vector_type(8))) short shortx8;

__device__ __forceinline__ unsigned short f32_to_bf16(float f){
  union { float f; unsigned int u; } x; x.f = f;
  unsigned int r = x.u + 0x7fffu + ((x.u >> 16) & 1u);
  return (unsigned short)(r >> 16);
}
__device__ __forceinline__ float bf16_to_f32(unsigned short h){
  union { unsigned int u; float f; } x; x.u = ((unsigned int)h) << 16;
  return x.f;
}
__device__ __forceinline__ float wave_sum(float v){
  #pragma unroll
  for (int o = 32; o > 0; o >>= 1) v += __shfl_down(v, o, 64);
  return v;
}
__device__ __forceinline__ void async16(const void* g, void* l){
  __builtin_amdgcn_global_load_lds((const __attribute__((address_space(1))) void*)g,
                                   (__attribute__((address_space(3))) void*)l, 16, 0, 0);
}

// ---------------- fp32 -> bf16 weight conversion (7 segments fused) ----------------
struct CvtArgs {
  const float* s[7];
  unsigned short* d[7];
  int n4[7];
};
__global__ __launch_bounds__(256) void cvt7_kernel(CvtArgs a){
  const int seg = blockIdx.y;
  const float* __restrict__ s = a.s[seg];
  unsigned short* __restrict__ d = a.d[seg];
  const int n4 = a.n4[seg];
  for (int i = blockIdx.x * 256 + threadIdx.x; i < n4; i += gridDim.x * 256) {
    float4 v = ((const float4*)s)[i];
    union { unsigned short u[4]; uint2 p; } o;
    o.u[0] = f32_to_bf16(v.x); o.u[1] = f32_to_bf16(v.y);
    o.u[2] = f32_to_bf16(v.z); o.u[3] = f32_to_bf16(v.w);
    *(uint2*)&d[(long)i * 4] = o.p;
  }
}

// ---------------- ln0: x_in -> x (fp32) ----------------
__global__ __launch_bounds__(256) void ln0_kernel(const float* __restrict__ xin,
    const float* __restrict__ w, const float* __restrict__ b, float* __restrict__ xo){
  const int row = blockIdx.x, tid = threadIdx.x;
  const float* xr = xin + (long)row * CCH;
  float c4[4]; float s = 0.f, s2 = 0.f;
  #pragma unroll
  for (int j = 0; j < 4; j++){ c4[j] = xr[tid + j*256]; s += c4[j]; s2 += c4[j]*c4[j]; }
  s = wave_sum(s); s2 = wave_sum(s2);
  __shared__ float red[2][4];
  const int wid = tid >> 6, lane = tid & 63;
  if (lane == 0){ red[0][wid] = s; red[1][wid] = s2; }
  __syncthreads();
  const float S  = red[0][0]+red[0][1]+red[0][2]+red[0][3];
  const float S2 = red[1][0]+red[1][1]+red[1][2]+red[1][3];
  const float inv = 1.f / CCH;
  const float m = S * inv;
  const float rs = rsqrtf(S2 * inv - m*m + EPSV);
  float* xout = xo + (long)row * CCH;
  #pragma unroll
  for (int j = 0; j < 4; j++){ int c = tid + j*256; xout[c] = (c4[j]-m)*rs*w[c] + b[c]; }
}

// ---------------- fused LN + time-shift + mix -> bf16 ----------------
template<int NOUT>
__global__ __launch_bounds__(256) void ln_mix(
    const float* __restrict__ x,
    const float* __restrict__ lw, const float* __restrict__ lb,
    const float* __restrict__ mk, const float* __restrict__ mv, const float* __restrict__ mr,
    unsigned short* __restrict__ xk, unsigned short* __restrict__ xv, unsigned short* __restrict__ xr)
{
  const int row = blockIdx.x;
  const int t = row & (TT - 1);
  const int tid = threadIdx.x;
  const float* xc = x + (long)row * CCH;
  const float* xp = xc - CCH;
  float c4[4], p4[4];
  float s1=0.f, s2=0.f, s3=0.f, s4=0.f;
  #pragma unroll
  for (int j = 0; j < 4; j++){
    const int c = tid + j*256;
    c4[j] = xc[c];
    p4[j] = (t > 0) ? xp[c] : 0.f;
    s1 += c4[j]; s2 += c4[j]*c4[j];
    s3 += p4[j]; s4 += p4[j]*p4[j];
  }
  s1 = wave_sum(s1); s2 = wave_sum(s2); s3 = wave_sum(s3); s4 = wave_sum(s4);
  __shared__ float red[4][4];
  const int wid = tid >> 6, lane = tid & 63;
  if (lane == 0){ red[wid][0]=s1; red[wid][1]=s2; red[wid][2]=s3; red[wid][3]=s4; }
  __syncthreads();
  const float S1 = red[0][0]+red[1][0]+red[2][0]+red[3][0];
  const float S2 = red[0][1]+red[1][1]+red[2][1]+red[3][1];
  const float S3 = red[0][2]+red[1][2]+red[2][2]+red[3][2];
  const float S4 = red[0][3]+red[1][3]+red[2][3]+red[3][3];
  const float inv = 1.f / CCH;
  const float m1 = S1*inv; const float r1 = rsqrtf(S2*inv - m1*m1 + EPSV);
  const float m0 = S3*inv; const float r0 = rsqrtf(S4*inv - m0*m0 + EPSV);
  #pragma unroll
  for (int j = 0; j < 4; j++){
    const int c = tid + j*256;
    const long o = (long)row * CCH + c;
    const float wv = lw[c], bv = lb[c];
    const float h  = (c4[j]-m1)*r1*wv + bv;
    const float hp = (t > 0) ? ((p4[j]-m0)*r0*wv + bv) : 0.f;
    const float a = mk[c]; xk[o] = f32_to_bf16(h*a + hp*(1.f-a));
    if (NOUT == 3){ const float q = mv[c]; xv[o] = f32_to_bf16(h*q + hp*(1.f-q)); }
    const float g = mr[c]; xr[o] = f32_to_bf16(h*g + hp*(1.f-g));
  }
}

// ---------------- WKV blocked scan ----------------
__global__ __launch_bounds__(256) void wkv_pass1(
    const unsigned short* __restrict__ kin, const unsigned short* __restrict__ vin,
    const float* __restrict__ td,
    float* __restrict__ sta, float* __restrict__ stb, float* __restrict__ stp)
{
  const int c = blockIdx.x * 256 + threadIdx.x;
  const int chunk = blockIdx.y, b = blockIdx.z;
  const float w = -__expf(td[c]);
  const long base = ((long)b * TT + (long)chunk * CHKL) * CCH + c;
  float aa = 0.f, bb = 0.f, pp = -1e38f;
  for (int t0 = 0; t0 < CHKL; t0 += 8) {
    float kr[8], vr[8];
    #pragma unroll
    for (int j = 0; j < 8; j++){
      const long o = base + (long)(t0 + j) * CCH;
      kr[j] = bf16_to_f32(kin[o]);
      vr[j] = bf16_to_f32(vin[o]);
    }
    #pragma unroll
    for (int j = 0; j < 8; j++){
      const float kk = kr[j], vv = vr[j];
      const float ww2 = pp + w;
      const float qq2 = fmaxf(ww2, kk);
      const float e1b = __expf(ww2 - qq2), e2b = __expf(kk - qq2);
      aa = e1b*aa + e2b*vv; bb = e1b*bb + e2b; pp = qq2;
    }
  }
  const long si = (long)chunk * 4096 + b * CCH + c;
  sta[si] = aa; stb[si] = bb; stp[si] = pp;
}

__global__ __launch_bounds__(256) void wkv_combine(
    const float* __restrict__ td,
    const float* __restrict__ sta, const float* __restrict__ stb, const float* __restrict__ stp,
    float* __restrict__ ina, float* __restrict__ inb, float* __restrict__ inp)
{
  const int idx = blockIdx.x * 256 + threadIdx.x;   // b*C + c
  const int c = idx & (CCH - 1);
  const float wn = -__expf(td[c]) * (float)CHKL;
  float a = 0.f, b = 0.f, p = -1e38f;
  for (int j0 = 0; j0 < NCHK; j0 += 8) {
    float la[8], lb[8], lp[8];
    #pragma unroll
    for (int j = 0; j < 8; j++){
      const long si = (long)(j0 + j) * 4096 + idx;
      la[j] = sta[si]; lb[j] = stb[si]; lp[j] = stp[si];
    }
    #pragma unroll
    for (int j = 0; j < 8; j++){
      const long si = (long)(j0 + j) * 4096 + idx;
      ina[si] = a; inb[si] = b; inp[si] = p;
      const float pd = p + wn;
      const float q = fmaxf(pd, lp[j]);
      const float e1 = __expf(pd - q), e2 = __expf(lp[j] - q);
      a = e1*a + e2*la[j]; b = e1*b + e2*lb[j]; p = q;
    }
  }
}

__global__ __launch_bounds__(256) void wkv_pass2(
    const unsigned short* __restrict__ kin, const unsigned short* __restrict__ vin,
    const unsigned short* __restrict__ srin,
    const float* __restrict__ td, const float* __restrict__ tf,
    const float* __restrict__ ina, const float* __restrict__ inb, const float* __restrict__ inp,
    unsigned short* __restrict__ out)
{
  const int c = blockIdx.x * 256 + threadIdx.x;
  const int chunk = blockIdx.y, b = blockIdx.z;
  const float w = -__expf(td[c]);
  const float u = tf[c];
  const long si = (long)chunk * 4096 + b * CCH + c;
  float aa = ina[si], bb = inb[si], pp = inp[si];
  const long base = ((long)b * TT + (long)chunk * CHKL) * CCH + c;
  for (int t0 = 0; t0 < CHKL; t0 += 8) {
    float kr[8], vr[8], sr[8];
    #pragma unroll
    for (int j = 0; j < 8; j++){
      const long o = base + (long)(t0 + j) * CCH;
      kr[j] = bf16_to_f32(kin[o]);
      vr[j] = bf16_to_f32(vin[o]);
      sr[j] = bf16_to_f32(srin[o]);
    }
    #pragma unroll
    for (int j = 0; j < 8; j++){
      const float kk = kr[j], vv = vr[j];
      const float ww = u + kk;
      const float qq = fmaxf(pp, ww);
      const float e1 = __expf(pp - qq), e2 = __expf(ww - qq);
      const float outv = (e1*aa + e2*vv) / (e1*bb + e2);
      const float ww2 = pp + w;
      const float qq2 = fmaxf(ww2, kk);
      const float e1b = __expf(ww2 - qq2), e2b = __expf(kk - qq2);
      aa = e1b*aa + e2b*vv; bb = e1b*bb + e2b; pp = qq2;
      out[base + (long)(t0 + j) * CCH] = f32_to_bf16(sr[j] * outv);
    }
  }
}

// ---------------- bf16 MFMA GEMM: C[M,N] = A[M,K] * W[N,K]^T ----------------
// R4-proven structure: BK=64, 2-barrier K-loop, XOR-swizzled LDS chunk
// placement (slot = chunk ^ (row&7)) -> 0 bank conflicts (verified R4).
// R5's single-barrier dbuf regressed (-67us) -> reverted. FFN1 merge kept.
#define BM 128
#define BN 128
#define BK 64

enum { EP_BF16 = 0, EP_ADD = 3, EP_MULADD = 4, EP_KVR = 5, EP_FFN1 = 6 };

template<int EPI>
__global__ __launch_bounds__(256) void gemm_bt(
    const unsigned short* __restrict__ A,
    const unsigned short* __restrict__ W,
    int N, const int K,
    unsigned short* __restrict__ outb,
    float* __restrict__ xres,
    const unsigned short* __restrict__ rr,
    const unsigned short* __restrict__ A2,
    const unsigned short* __restrict__ W2,
    unsigned short* __restrict__ outb2,
    const int N2)
{
  const int bm = blockIdx.x;
  int bn = blockIdx.y;
  bool sig = false;
  if (EPI == EP_KVR) {
    const long z = blockIdx.z;
    const long Mfull = (long)gridDim.x * BM;
    A    += z * Mfull * K;
    W    += z * (long)N * K;
    outb += z * Mfull * N;
    sig = (blockIdx.z == 2);
  }
  if (EPI == EP_FFN1) {
    if (blockIdx.z == 1) {
      if (bn >= N2 / BN) return;   // block-uniform early-exit, before any barrier
      A = A2; W = W2; outb = outb2; N = N2; sig = true;
    }
  }
  __shared__ unsigned short lA[BM * BK];   // 16 KB
  __shared__ unsigned short lW[BN * BK];   // 16 KB
  const int tid = threadIdx.x;
  const int wid = tid >> 6, lane = tid & 63;
  const int wm = (wid >> 1) * 64, wn = (wid & 1) * 64;
  const int quad = lane >> 4, r16 = lane & 15;

  // staging: thread tid, call i -> LDS chunk position P = i*256 + tid
  // row = P>>3 = i*32 + (tid>>3); stored slot = tid&7; logical chunk = slot ^ (row&7)
  const int srow = tid >> 3;
  const int scol = (tid & 7) ^ (srow & 7);
  const unsigned short* Ag = A + ((long)(bm * BM + srow)) * K + scol * 8;
  const unsigned short* Wg = W + ((long)(bn * BN + srow)) * K + scol * 8;
  const long rs32 = (long)32 * K;

  // fragment-read swizzle offsets (in shorts): chunk c = kk*4+quad at row R
  // -> addr = R*64 + ((kk*4+quad) ^ (R&7))*8, and R&7 == r16&7 here.
  const int sw0 = ((quad)     ^ (r16 & 7)) * 8;
  const int sw1 = ((4 + quad) ^ (r16 & 7)) * 8;

  const floatx4 zf = {0.f, 0.f, 0.f, 0.f};
  floatx4 acc[4][4];
  #pragma unroll
  for (int i = 0; i < 4; i++)
    #pragma unroll
    for (int j = 0; j < 4; j++) acc[i][j] = zf;

  for (int k0 = 0; k0 < K; k0 += BK) {
    __syncthreads();
    #pragma unroll
    for (int i = 0; i < 4; i++) {
      async16(Ag + (long)i * rs32 + k0, &lA[(i * 256 + wid * 64) * 8]);
      async16(Wg + (long)i * rs32 + k0, &lW[(i * 256 + wid * 64) * 8]);
    }
    __syncthreads();
    #pragma unroll
    for (int kk = 0; kk < 2; kk++) {
      const int sw = kk ? sw1 : sw0;
      shortx8 af[4], bf[4];
      #pragma unroll
      for (int m = 0; m < 4; m++) af[m] = *(const shortx8*)&lA[(wm + m*16 + r16) * 64 + sw];
      #pragma unroll
      for (int n = 0; n < 4; n++) bf[n] = *(const shortx8*)&lW[(wn + n*16 + r16) * 64 + sw];
      #pragma unroll
      for (int m = 0; m < 4; m++)
        #pragma unroll
        for (int n = 0; n < 4; n++)
          acc[m][n] = __builtin_amdgcn_mfma_f32_16x16x32_bf16(af[m], bf[n], acc[m][n], 0, 0, 0);
    }
  }

  const int colBase = bn * BN + wn + r16;
  #pragma unroll
  for (int m = 0; m < 4; m++) {
    const int rowBase = bm * BM + wm + m * 16 + quad * 4;
    #pragma unroll
    for (int n = 0; n < 4; n++) {
      const int col = colBase + n * 16;
      #pragma unroll
      for (int r = 0; r < 4; r++) {
        const long idx = (long)(rowBase + r) * N + col;
        const float val = acc[m][n][r];
        if (EPI == EP_KVR)       outb[idx] = sig ? f32_to_bf16(1.f / (1.f + __expf(-val)))
                                                 : f32_to_bf16(val);
        else if (EPI == EP_FFN1) {
          if (sig) outb[idx] = f32_to_bf16(1.f / (1.f + __expf(-val)));
          else     { const float t = val > 0.f ? val : 0.f; outb[idx] = f32_to_bf16(t * t); }
        }
        else if (EPI == EP_ADD)  xres[idx] += val;
        else if (EPI == EP_MULADD) xres[idx] = fmaf(bf16_to_f32(rr[idx]), val, xres[idx]);
        else                     outb[idx] = f32_to_bf16(val);
      }
    }
  }
}

extern "C" void kernel_launch(void* const* d_in, const int* in_sizes, int n_in,
                              void* d_out, int out_size, void* d_ws, size_t ws_size,
                              hipStream_t stream)
{
  const float* x_in       = (const float*)d_in[0];
  const float* ln0_w      = (const float*)d_in[1];
  const float* ln0_b      = (const float*)d_in[2];
  const float* ln1_w      = (const float*)d_in[3];
  const float* ln1_b      = (const float*)d_in[4];
  const float* ln2_w      = (const float*)d_in[5];
  const float* ln2_b      = (const float*)d_in[6];
  const float* time_decay = (const float*)d_in[7];
  const float* time_first = (const float*)d_in[8];
  const float* tmk        = (const float*)d_in[9];
  const float* tmv        = (const float*)d_in[10];
  const float* tmr        = (const float*)d_in[11];
  const float* Wk         = (const float*)d_in[12];
  const float* Wv         = (const float*)d_in[13];
  const float* Wr         = (const float*)d_in[14];
  const float* Wo         = (const float*)d_in[15];
  const float* cmk        = (const float*)d_in[16];
  const float* cmr        = (const float*)d_in[17];
  const float* Wck        = (const float*)d_in[18];
  const float* Wcv        = (const float*)d_in[19];
  const float* Wcr        = (const float*)d_in[20];
  float* x = (float*)d_out;

  const int M = 4 * TT;                 // 8192 rows
  const long lCC = (long)CCH * CCH;
  const long lFC = (long)FFD * CCH;
  const long MC  = (long)M * CCH;

  unsigned short* wsl  = (unsigned short*)d_ws;
  unsigned short* wkb  = wsl;
  unsigned short* wvb  = wkb + lCC;
  unsigned short* wrb  = wvb + lCC;
  unsigned short* wob  = wrb + lCC;
  unsigned short* wcrb = wob + lCC;
  unsigned short* wckb = wcrb + lCC;
  unsigned short* wcvb = wckb + lFC;
  unsigned short* xk   = wcvb + lFC;
  unsigned short* xv   = xk + MC;
  unsigned short* xr   = xv + MC;
  unsigned short* kbuf = xr + MC;       // region reused as kf [M,F]
  unsigned short* vbuf = kbuf + MC;
  unsigned short* sbuf = vbuf + MC;
  unsigned short* kfb  = kbuf;
  unsigned short* rrb  = kbuf + (long)M * FFD;

  // WKV scan state in the (dead between GEMMs) xk region
  float* sta = (float*)xk;
  float* stb = sta + (long)NCHK * 4096;
  float* stp = stb + (long)NCHK * 4096;
  float* ina = stp + (long)NCHK * 4096;
  float* inb = ina + (long)NCHK * 4096;
  float* inp = inb + (long)NCHK * 4096;

  ln0_kernel<<<M, 256, 0, stream>>>(x_in, ln0_w, ln0_b, x);

  const dim3 g1(M / BM, CCH / BN);      // (64, 8)
  const dim3 gkvr(M / BM, CCH / BN, 3); // (64, 8, 3)
  const dim3 gffn(M / BM, FFD / BN, 2); // (64, 32, 2): z0 = key relu2, z1 = r sigmoid
  const dim3 gw(CCH / 256, NCHK, 4);    // (4, 32, 4)

  for (int l = 0; l < 4; l++) {
    CvtArgs ca;
    ca.s[0] = Wk  + (long)l * lCC; ca.d[0] = wkb;  ca.n4[0] = (int)(lCC / 4);
    ca.s[1] = Wv  + (long)l * lCC; ca.d[1] = wvb;  ca.n4[1] = (int)(lCC / 4);
    ca.s[2] = Wr  + (long)l * lCC; ca.d[2] = wrb;  ca.n4[2] = (int)(lCC / 4);
    ca.s[3] = Wo  + (long)l * lCC; ca.d[3] = wob;  ca.n4[3] = (int)(lCC / 4);
    ca.s[4] = Wcr + (long)l * lCC; ca.d[4] = wcrb; ca.n4[4] = (int)(lCC / 4);
    ca.s[5] = Wck + (long)l * lFC; ca.d[5] = wckb; ca.n4[5] = (int)(lFC / 4);
    ca.s[6] = Wcv + (long)l * lFC; ca.d[6] = wcvb; ca.n4[6] = (int)(lFC / 4);
    cvt7_kernel<<<dim3(512, 7), 256, 0, stream>>>(ca);

    const float* td_l = time_decay + l*CCH;
    const float* tf_l = time_first + l*CCH;

    // --- TimeMix ---
    ln_mix<3><<<M, 256, 0, stream>>>(x, ln1_w + l*CCH, ln1_b + l*CCH,
                                     tmk + l*CCH, tmv + l*CCH, tmr + l*CCH, xk, xv, xr);
    gemm_bt<EP_KVR><<<gkvr, 256, 0, stream>>>(xk, wkb, CCH, CCH, kbuf, nullptr, nullptr,
                                              nullptr, nullptr, nullptr, 0);
    wkv_pass1 <<<gw, 256, 0, stream>>>(kbuf, vbuf, td_l, sta, stb, stp);
    wkv_combine<<<16, 256, 0, stream>>>(td_l, sta, stb, stp, ina, inb, inp);
    wkv_pass2 <<<gw, 256, 0, stream>>>(kbuf, vbuf, sbuf, td_l, tf_l, ina, inb, inp, xv);
    gemm_bt<EP_ADD ><<<g1, 256, 0, stream>>>(xv, wob, CCH, CCH, nullptr, x, nullptr,
                                             nullptr, nullptr, nullptr, 0);

    // --- ChannelMix ---
    ln_mix<2><<<M, 256, 0, stream>>>(x, ln2_w + l*CCH, ln2_b + l*CCH,
                                     cmk + l*CCH, nullptr, cmr + l*CCH, xk, nullptr, xr);
    gemm_bt<EP_FFN1><<<gffn, 256, 0, stream>>>(xk, wckb, FFD, CCH, kfb, nullptr, nullptr,
                                               xr, wcrb, rrb, CCH);
    gemm_bt<EP_MULADD><<<g1, 256, 0, stream>>>(kfb, wcvb, CCH, FFD, nullptr, x, rrb,
                                               nullptr, nullptr, nullptr, 0);
  }
}